// Round 3
// baseline (13587.856 us; speedup 1.0000x reference)
//
#include <hip/hip_runtime.h>
#include <hip/hip_bf16.h>
#include <math.h>

#define BATCH 64
#define TLEN  512
#define DIN   300
#define RDIM  2048
#define HELEMS (BATCH * RDIM)
#define NBLK 256

typedef __attribute__((ext_vector_type(4))) float f32x4;
typedef __attribute__((ext_vector_type(8))) short bf16x8;

__device__ __forceinline__ unsigned short f32_bf16_rne(float f) {
    unsigned int u = __float_as_uint(f);
    u += 0x7fffu + ((u >> 16) & 1u);
    return (unsigned short)(u >> 16);
}
__device__ __forceinline__ float bf16_f32(unsigned short h) {
    return __uint_as_float(((unsigned int)h) << 16);
}

// ---------------- W -> bf16 hi/lo split (one-time) + barrier reset ----------------
__global__ __launch_bounds__(256) void k_wsplit(const float* __restrict__ W,
                                                unsigned short* __restrict__ Whi,
                                                unsigned short* __restrict__ Wlo,
                                                unsigned* __restrict__ bar) {
    if (blockIdx.x == 0) {
        __hip_atomic_store(&bar[threadIdx.x], 0u, __ATOMIC_RELAXED, __HIP_MEMORY_SCOPE_AGENT);
        __hip_atomic_store(&bar[threadIdx.x + 256], 0u, __ATOMIC_RELAXED, __HIP_MEMORY_SCOPE_AGENT);
    }
    int i = (blockIdx.x * 256 + threadIdx.x) * 4;
    f32x4 w = *(const f32x4*)(W + i);
    ushort4 hi, lo;
    unsigned short h0 = f32_bf16_rne(w[0]); hi.x = h0; lo.x = f32_bf16_rne(w[0] - bf16_f32(h0));
    unsigned short h1 = f32_bf16_rne(w[1]); hi.y = h1; lo.y = f32_bf16_rne(w[1] - bf16_f32(h1));
    unsigned short h2 = f32_bf16_rne(w[2]); hi.z = h2; lo.z = f32_bf16_rne(w[2] - bf16_f32(h2));
    unsigned short h3 = f32_bf16_rne(w[3]); hi.w = h3; lo.w = f32_bf16_rne(w[3] - bf16_f32(h3));
    *(ushort4*)(Whi + i) = hi;
    *(ushort4*)(Wlo + i) = lo;
}

// ---------------- Kernel A: U = x @ Win^T (fp32), writes into out ----------------
#define A_BM 128
#define A_BN 64
#define A_BK 20
#define XS_STRIDE 132
#define WS_STRIDE 68

__global__ __launch_bounds__(256) void k_proj(const float* __restrict__ x,
                                              const float* __restrict__ Win,
                                              float* __restrict__ hseq,
                                              unsigned short* h0hi,
                                              unsigned short* h0lo,
                                              int do_split) {
    __shared__ __align__(16) float xs[A_BK * XS_STRIDE];
    __shared__ __align__(16) float wsh[A_BK * WS_STRIDE];
    const int tid = threadIdx.x;
    const int tx = tid & 15;
    const int ty = tid >> 4;
    const int m0 = blockIdx.y * A_BM;
    const int n0 = blockIdx.x * A_BN;

    float acc[8][4];
#pragma unroll
    for (int i = 0; i < 8; ++i)
#pragma unroll
        for (int j = 0; j < 4; ++j) acc[i][j] = 0.0f;

    for (int k0 = 0; k0 < DIN; k0 += A_BK) {
#pragma unroll
        for (int s = 0; s < (A_BM * A_BK) / 256; ++s) {
            int idx = tid + s * 256;
            int row = idx / A_BK, col = idx - row * A_BK;
            xs[col * XS_STRIDE + row] = x[(m0 + row) * DIN + k0 + col];
        }
#pragma unroll
        for (int s = 0; s < (A_BN * A_BK) / 256; ++s) {
            int idx = tid + s * 256;
            int row = idx / A_BK, col = idx - row * A_BK;
            wsh[col * WS_STRIDE + row] = Win[(n0 + row) * DIN + k0 + col];
        }
        __syncthreads();
#pragma unroll
        for (int kk = 0; kk < A_BK; ++kk) {
            f32x4 xv0 = *(const f32x4*)&xs[kk * XS_STRIDE + ty * 8];
            f32x4 xv1 = *(const f32x4*)&xs[kk * XS_STRIDE + ty * 8 + 4];
            f32x4 wv  = *(const f32x4*)&wsh[kk * WS_STRIDE + tx * 4];
#pragma unroll
            for (int i = 0; i < 4; ++i)
#pragma unroll
                for (int j = 0; j < 4; ++j) acc[i][j] += xv0[i] * wv[j];
#pragma unroll
            for (int i = 0; i < 4; ++i)
#pragma unroll
                for (int j = 0; j < 4; ++j) acc[4 + i][j] += xv1[i] * wv[j];
        }
        __syncthreads();
    }

#pragma unroll
    for (int i = 0; i < 8; ++i) {
        int m = m0 + ty * 8 + i;
        int t = m & (TLEN - 1);
        int b = m >> 9;
        int r0 = n0 + tx * 4;
        f32x4 v;
#pragma unroll
        for (int j = 0; j < 4; ++j) v[j] = acc[i][j];
        if (t == 0) {
#pragma unroll
            for (int j = 0; j < 4; ++j) v[j] = tanhf(v[j]);
            if (do_split) {
#pragma unroll
                for (int j = 0; j < 4; ++j) {
                    unsigned short hi = f32_bf16_rne(v[j]);
                    h0hi[b * RDIM + r0 + j] = hi;
                    h0lo[b * RDIM + r0 + j] = f32_bf16_rne(v[j] - bf16_f32(hi));
                }
            }
        }
        *(f32x4*)(hseq + ((size_t)t * BATCH + b) * RDIM + r0) = v;
    }
}

// ---------------- Persistent step kernel: all t = 1..511 ----------------
// 256 blocks (1/CU) x 512 threads (8 waves). Block nb: n0 = (nb>>1)*16 reservoir
// cols, m0 = (nb&1)*32 batch rows. W rows n0..n0+15 (hi+lo) pinned in LDS as MFMA
// A-operand fragments. Waves: mt = wave&1 (16-batch subtile), kq = wave>>1 (K
// quarter, 512 each). MFMA computes D = W_frag * h_frag: D row = n (v-index,
// stride-1), col = batch. 3-way LDS partial reduce across kq. Cross-block h via
// agent-scope write-through atomics; two-level monotonic barrier; acquire fence.
__global__ __launch_bounds__(512, 1) void k_steps(float* __restrict__ hseq,
                                                  const unsigned short* __restrict__ Whi,
                                                  const unsigned short* __restrict__ Wlo,
                                                  unsigned short* __restrict__ hb,
                                                  unsigned* __restrict__ bar) {
    __shared__ __align__(16) unsigned short ldsBhi[64 * 64 * 8];  // 64 KB
    __shared__ __align__(16) unsigned short ldsBlo[64 * 64 * 8];  // 64 KB
    __shared__ float red[3][2][16][17];                           // 6.5 KB

    const int tid  = threadIdx.x;
    const int lane = tid & 63;
    const int wave = tid >> 6;
    const int l15  = lane & 15;
    const int q    = lane >> 4;
    const int mt   = wave & 1;
    const int kq   = wave >> 1;
    const int nb   = blockIdx.x;
    const int n0   = (nb >> 1) * 16;
    const int m0   = (nb & 1) * 32;

    // ---- stage W fragments into LDS (once) ----
    // frag[(c*64 + l)*8 + j] = W[n0 + (l&15)][c*32 + (l>>4)*8 + j]
    for (int it = tid; it < 64 * 64; it += 512) {
        int c = it >> 6, l = it & 63;
        size_t src = (size_t)(n0 + (l & 15)) * RDIM + c * 32 + ((l >> 4) << 3);
        *(bf16x8*)(ldsBhi + (size_t)it * 8) = *(const bf16x8*)(Whi + src);
        *(bf16x8*)(ldsBlo + (size_t)it * 8) = *(const bf16x8*)(Wlo + src);
    }
    __syncthreads();

    // h fragment (B-operand): rows = batch m0+mt*16+l15, K-quarter kq
    const int hrow = m0 + mt * 16 + l15;
    const size_t hbase = (size_t)hrow * RDIM + kq * 512 + q * 8;
    const unsigned short* wh_base = ldsBhi + (size_t)(kq * 16) * 64 * 8;
    const unsigned short* wl_base = ldsBlo + (size_t)(kq * 16) * 64 * 8;

    // epilogue (kq==0 waves): batch row b = m0+mt*16+l15, cols n0+q*4..+3 (contig)
    const int eb = m0 + mt * 16 + l15;
    const size_t obase = (size_t)eb * RDIM + n0 + q * 4;

    float hreg[4] = {0.f, 0.f, 0.f, 0.f};
    unsigned* gslot = &bar[(nb & 7) * 32];
    unsigned* gcnt  = &bar[256];

    for (int t = 1; t < TLEN; ++t) {
        const unsigned short* hphi = hb + (size_t)(((t - 1) & 1) * 2) * HELEMS;
        const unsigned short* hplo = hphi + HELEMS;
        unsigned short* hchi = hb + (size_t)((t & 1) * 2) * HELEMS;
        unsigned short* hclo = hchi + HELEMS;
        float* outt = hseq + (size_t)t * HELEMS;

        // prefetch U_t (hidden under the MFMA loop)
        f32x4 u4;
        if (kq == 0) u4 = *(const f32x4*)(outt + obase);

        const unsigned short* ah = hphi + hbase;
        const unsigned short* al = hplo + hbase;

        f32x4 acc0 = {0.f, 0.f, 0.f, 0.f};
        f32x4 acc1 = {0.f, 0.f, 0.f, 0.f};
        f32x4 acc2 = {0.f, 0.f, 0.f, 0.f};
        f32x4 acc3 = {0.f, 0.f, 0.f, 0.f};
#pragma unroll
        for (int c = 0; c < 16; ++c) {
            bf16x8 hhi = *(const bf16x8*)(ah + c * 32);
            bf16x8 hlo = *(const bf16x8*)(al + c * 32);
            bf16x8 whi = *(const bf16x8*)(wh_base + (size_t)(c * 64 + lane) * 8);
            bf16x8 wlo = *(const bf16x8*)(wl_base + (size_t)(c * 64 + lane) * 8);
            f32x4* a = (c & 2) ? ((c & 1) ? &acc3 : &acc2) : ((c & 1) ? &acc1 : &acc0);
            *a = __builtin_amdgcn_mfma_f32_16x16x32_bf16(whi, hhi, *a, 0, 0, 0);
            *a = __builtin_amdgcn_mfma_f32_16x16x32_bf16(whi, hlo, *a, 0, 0, 0);
            *a = __builtin_amdgcn_mfma_f32_16x16x32_bf16(wlo, hhi, *a, 0, 0, 0);
        }
        f32x4 acc;
#pragma unroll
        for (int v = 0; v < 4; ++v) acc[v] = (acc0[v] + acc1[v]) + (acc2[v] + acc3[v]);

        if (kq != 0) {
#pragma unroll
            for (int v = 0; v < 4; ++v) red[kq - 1][mt][q * 4 + v][l15] = acc[v];
        }
        __syncthreads();

        if (kq == 0) {
            unsigned long long phi = 0ull, plo = 0ull;
            f32x4 hout;
#pragma unroll
            for (int v = 0; v < 4; ++v) {
                float tot = ((acc[v] + red[0][mt][q * 4 + v][l15]) +
                             (red[1][mt][q * 4 + v][l15] + red[2][mt][q * 4 + v][l15]));
                float raw = tanhf(tot + u4[v]);
                float h = (t >= 2) ? 0.5f * raw + 0.5f * hreg[v] : raw;
                hreg[v] = h;
                hout[v] = h;
                unsigned short hi = f32_bf16_rne(h);
                phi |= (unsigned long long)hi << (16 * v);
                plo |= (unsigned long long)f32_bf16_rne(h - bf16_f32(hi)) << (16 * v);
            }
            *(f32x4*)(outt + obase) = hout;  // block-private, plain store
            // cross-block: write-through to coherence point (bypass L2)
            __hip_atomic_store((unsigned long long*)(hchi + obase), phi,
                               __ATOMIC_RELAXED, __HIP_MEMORY_SCOPE_AGENT);
            __hip_atomic_store((unsigned long long*)(hclo + obase), plo,
                               __ATOMIC_RELAXED, __HIP_MEMORY_SCOPE_AGENT);
        }

        if (t + 1 < TLEN) {
            // drain this wave's stores, then block-level join
            asm volatile("s_waitcnt vmcnt(0)" ::: "memory");
            __syncthreads();
            if (tid == 0) {
                unsigned old = __hip_atomic_fetch_add(gslot, 1u, __ATOMIC_RELAXED,
                                                      __HIP_MEMORY_SCOPE_AGENT);
                if (old == (unsigned)t * 32u - 1u) {
                    __hip_atomic_fetch_add(gcnt, 1u, __ATOMIC_RELAXED,
                                           __HIP_MEMORY_SCOPE_AGENT);
                }
                while (__hip_atomic_load(gcnt, __ATOMIC_RELAXED,
                                         __HIP_MEMORY_SCOPE_AGENT) < (unsigned)t * 8u) {
                    __builtin_amdgcn_s_sleep(1);
                }
            }
            __syncthreads();
            // invalidate stale L1/L2 lines before reading the new h
            __builtin_amdgcn_fence(__ATOMIC_ACQUIRE, "agent");
        }
    }
}

// ---------------- Fallback step kernel (no workspace) ----------------
__global__ __launch_bounds__(256) void k_step_f32(float* hseq,
                                                  const float* __restrict__ Wf,
                                                  int t) {
    const int lane = threadIdx.x & 63;
    const int wave = threadIdx.x >> 6;
    const int l15 = lane & 15;
    const int q = lane >> 4;
    const int n0 = blockIdx.x * 16;
    const int m0 = wave * 16;

    const int arow = m0 + l15;
    const int brow = n0 + l15;
    const int kbase = q * 8;

    f32x4 acc = {0.f, 0.f, 0.f, 0.f};
    const float* hprev_f = hseq + (size_t)(t - 1) * BATCH * RDIM;
    const float* af = hprev_f + arow * RDIM + kbase;
    const float* bfp = Wf + brow * RDIM + kbase;
#pragma unroll 2
    for (int k = 0; k < RDIM; k += 32) {
        f32x4 a0 = *(const f32x4*)(af + k);
        f32x4 a1 = *(const f32x4*)(af + k + 4);
        f32x4 b0 = *(const f32x4*)(bfp + k);
        f32x4 b1 = *(const f32x4*)(bfp + k + 4);
        bf16x8 ahi, alo, bhi, blo;
#pragma unroll
        for (int j = 0; j < 4; ++j) {
            unsigned short h;
            h = f32_bf16_rne(a0[j]); ahi[j] = (short)h; alo[j] = (short)f32_bf16_rne(a0[j] - bf16_f32(h));
            h = f32_bf16_rne(a1[j]); ahi[4 + j] = (short)h; alo[4 + j] = (short)f32_bf16_rne(a1[j] - bf16_f32(h));
            h = f32_bf16_rne(b0[j]); bhi[j] = (short)h; blo[j] = (short)f32_bf16_rne(b0[j] - bf16_f32(h));
            h = f32_bf16_rne(b1[j]); bhi[4 + j] = (short)h; blo[4 + j] = (short)f32_bf16_rne(b1[j] - bf16_f32(h));
        }
        acc = __builtin_amdgcn_mfma_f32_16x16x32_bf16(ahi, bhi, acc, 0, 0, 0);
        acc = __builtin_amdgcn_mfma_f32_16x16x32_bf16(alo, bhi, acc, 0, 0, 0);
        acc = __builtin_amdgcn_mfma_f32_16x16x32_bf16(ahi, blo, acc, 0, 0, 0);
    }

    float* outt = hseq + (size_t)t * BATCH * RDIM;
#pragma unroll
    for (int v = 0; v < 4; ++v) {
        int b = m0 + q * 4 + v;
        size_t o = (size_t)b * RDIM + brow;
        float raw = tanhf(acc[v] + outt[o]);
        float hp = hprev_f[o];
        float h = (t >= 2) ? 0.5f * raw + 0.5f * hp : raw;
        outt[o] = h;
    }
}

extern "C" void kernel_launch(void* const* d_in, const int* in_sizes, int n_in,
                              void* d_out, int out_size, void* d_ws, size_t ws_size,
                              hipStream_t stream) {
    const float* x   = (const float*)d_in[0];
    const float* Win = (const float*)d_in[1];
    const float* W   = (const float*)d_in[2];
    float* out = (float*)d_out;

    const size_t wElems = (size_t)RDIM * RDIM;
    const size_t hElems = (size_t)BATCH * RDIM;
    const size_t need = wElems * 2 * sizeof(unsigned short) +
                        hElems * 4 * sizeof(unsigned short) + 4096;
    const bool split = ws_size >= need;

    unsigned short* Whi = (unsigned short*)d_ws;
    unsigned short* Wlo = Whi + wElems;
    unsigned short* hb  = Wlo + wElems;
    unsigned* bar = (unsigned*)(hb + 4 * hElems);
    unsigned short* h0hi = hb;            // hi buffer for t=0 (parity 0)
    unsigned short* h0lo = hb + hElems;   // lo buffer for t=0

    if (split) {
        k_wsplit<<<(int)(wElems / 1024), 256, 0, stream>>>(W, Whi, Wlo, bar);
    }

    dim3 gA(RDIM / A_BN, (BATCH * TLEN) / A_BM);
    k_proj<<<gA, 256, 0, stream>>>(x, Win, out, split ? h0hi : nullptr,
                                   split ? h0lo : nullptr, split ? 1 : 0);

    if (split) {
        float* outp = out;
        unsigned short* Whip = Whi;
        unsigned short* Wlop = Wlo;
        unsigned short* hbp = hb;
        unsigned* barp = bar;
        void* args[5] = { &outp, &Whip, &Wlop, &hbp, &barp };
        hipLaunchCooperativeKernel((const void*)k_steps, dim3(256), dim3(512),
                                   args, 0, stream);
    } else {
        for (int t = 1; t < TLEN; ++t) {
            k_step_f32<<<RDIM / 16, 256, 0, stream>>>(out, W, t);
        }
    }
}

// Round 4
// 6929.825 us; speedup vs baseline: 1.9608x; 1.9608x over previous
//
#include <hip/hip_runtime.h>
#include <hip/hip_bf16.h>
#include <math.h>

#define BATCH 64
#define TLEN  512
#define DIN   300
#define RDIM  2048
#define HELEMS (BATCH * RDIM)
#define NBLK 256
#define HPAR 8   // h-buffer rotation depth (fence every HPAR steps)

typedef __attribute__((ext_vector_type(4))) float f32x4;
typedef __attribute__((ext_vector_type(8))) short bf16x8;

__device__ __forceinline__ unsigned short f32_bf16_rne(float f) {
    unsigned int u = __float_as_uint(f);
    u += 0x7fffu + ((u >> 16) & 1u);
    return (unsigned short)(u >> 16);
}
__device__ __forceinline__ float bf16_f32(unsigned short h) {
    return __uint_as_float(((unsigned int)h) << 16);
}

// ---------------- W -> bf16 hi/lo split (one-time) + barrier reset ----------------
__global__ __launch_bounds__(256) void k_wsplit(const float* __restrict__ W,
                                                unsigned short* __restrict__ Whi,
                                                unsigned short* __restrict__ Wlo,
                                                unsigned* __restrict__ bar) {
    if (blockIdx.x == 0) {
        __hip_atomic_store(&bar[threadIdx.x], 0u, __ATOMIC_RELAXED, __HIP_MEMORY_SCOPE_AGENT);
        __hip_atomic_store(&bar[threadIdx.x + 256], 0u, __ATOMIC_RELAXED, __HIP_MEMORY_SCOPE_AGENT);
    }
    int i = (blockIdx.x * 256 + threadIdx.x) * 4;
    f32x4 w = *(const f32x4*)(W + i);
    ushort4 hi, lo;
    unsigned short h0 = f32_bf16_rne(w[0]); hi.x = h0; lo.x = f32_bf16_rne(w[0] - bf16_f32(h0));
    unsigned short h1 = f32_bf16_rne(w[1]); hi.y = h1; lo.y = f32_bf16_rne(w[1] - bf16_f32(h1));
    unsigned short h2 = f32_bf16_rne(w[2]); hi.z = h2; lo.z = f32_bf16_rne(w[2] - bf16_f32(h2));
    unsigned short h3 = f32_bf16_rne(w[3]); hi.w = h3; lo.w = f32_bf16_rne(w[3] - bf16_f32(h3));
    *(ushort4*)(Whi + i) = hi;
    *(ushort4*)(Wlo + i) = lo;
}

// ---------------- Kernel A: U = x @ Win^T (fp32), writes into out ----------------
#define A_BM 128
#define A_BN 64
#define A_BK 20
#define XS_STRIDE 132
#define WS_STRIDE 68

__global__ __launch_bounds__(256) void k_proj(const float* __restrict__ x,
                                              const float* __restrict__ Win,
                                              float* __restrict__ hseq,
                                              unsigned short* h0hi,
                                              unsigned short* h0lo,
                                              int do_split) {
    __shared__ __align__(16) float xs[A_BK * XS_STRIDE];
    __shared__ __align__(16) float wsh[A_BK * WS_STRIDE];
    const int tid = threadIdx.x;
    const int tx = tid & 15;
    const int ty = tid >> 4;
    const int m0 = blockIdx.y * A_BM;
    const int n0 = blockIdx.x * A_BN;

    float acc[8][4];
#pragma unroll
    for (int i = 0; i < 8; ++i)
#pragma unroll
        for (int j = 0; j < 4; ++j) acc[i][j] = 0.0f;

    for (int k0 = 0; k0 < DIN; k0 += A_BK) {
#pragma unroll
        for (int s = 0; s < (A_BM * A_BK) / 256; ++s) {
            int idx = tid + s * 256;
            int row = idx / A_BK, col = idx - row * A_BK;
            xs[col * XS_STRIDE + row] = x[(m0 + row) * DIN + k0 + col];
        }
#pragma unroll
        for (int s = 0; s < (A_BN * A_BK) / 256; ++s) {
            int idx = tid + s * 256;
            int row = idx / A_BK, col = idx - row * A_BK;
            wsh[col * WS_STRIDE + row] = Win[(n0 + row) * DIN + k0 + col];
        }
        __syncthreads();
#pragma unroll
        for (int kk = 0; kk < A_BK; ++kk) {
            f32x4 xv0 = *(const f32x4*)&xs[kk * XS_STRIDE + ty * 8];
            f32x4 xv1 = *(const f32x4*)&xs[kk * XS_STRIDE + ty * 8 + 4];
            f32x4 wv  = *(const f32x4*)&wsh[kk * WS_STRIDE + tx * 4];
#pragma unroll
            for (int i = 0; i < 4; ++i)
#pragma unroll
                for (int j = 0; j < 4; ++j) acc[i][j] += xv0[i] * wv[j];
#pragma unroll
            for (int i = 0; i < 4; ++i)
#pragma unroll
                for (int j = 0; j < 4; ++j) acc[4 + i][j] += xv1[i] * wv[j];
        }
        __syncthreads();
    }

#pragma unroll
    for (int i = 0; i < 8; ++i) {
        int m = m0 + ty * 8 + i;
        int t = m & (TLEN - 1);
        int b = m >> 9;
        int r0 = n0 + tx * 4;
        f32x4 v;
#pragma unroll
        for (int j = 0; j < 4; ++j) v[j] = acc[i][j];
        if (t == 0) {
#pragma unroll
            for (int j = 0; j < 4; ++j) v[j] = tanhf(v[j]);
            if (do_split) {
#pragma unroll
                for (int j = 0; j < 4; ++j) {
                    unsigned short hi = f32_bf16_rne(v[j]);
                    h0hi[b * RDIM + r0 + j] = hi;
                    h0lo[b * RDIM + r0 + j] = f32_bf16_rne(v[j] - bf16_f32(hi));
                }
            }
        }
        *(f32x4*)(hseq + ((size_t)t * BATCH + b) * RDIM + r0) = v;
    }
}

// ---------------- Persistent step kernel: all t = 1..511 ----------------
// 256 blocks (1/CU) x 256 threads (4 waves). Block nb: n0 = (nb>>1)*16 reservoir
// cols, m0 = (nb&1)*32 batch rows. W rows n0..n0+15 (hi+lo) pinned in LDS as MFMA
// A-operand fragments. Waves: mt = wave&1 (16-batch subtile), kh = wave>>1 (K half).
// h rotates over HPAR=8 parity buffers so plain CACHED loads are safe; a single
// agent-acquire fence every 8 steps invalidates would-be-stale lines. On the other
// 7 steps L2 serves the 32-block intra-XCD h re-reads (first toucher fills L2).
// Cross-block h published via agent-scope write-through atomics; two-level
// monotonic-counter barrier (no wbl2).
__global__ __launch_bounds__(256, 1) void k_steps(float* __restrict__ hseq,
                                                  const unsigned short* __restrict__ Whi,
                                                  const unsigned short* __restrict__ Wlo,
                                                  unsigned short* __restrict__ hb,
                                                  unsigned* __restrict__ bar) {
    __shared__ __align__(16) unsigned short ldsBhi[64 * 64 * 8];  // 64 KB
    __shared__ __align__(16) unsigned short ldsBlo[64 * 64 * 8];  // 64 KB
    __shared__ float red[2][16][17];

    const int tid  = threadIdx.x;
    const int lane = tid & 63;
    const int wave = tid >> 6;
    const int l15  = lane & 15;
    const int q    = lane >> 4;
    const int mt   = wave & 1;
    const int kh   = wave >> 1;
    const int nb   = blockIdx.x;
    const int n0   = (nb >> 1) * 16;
    const int m0   = (nb & 1) * 32;

    // ---- stage W fragments into LDS (once) ----
    // frag[(c*64 + l)*8 + j] = W[n0 + (l&15)][c*32 + (l>>4)*8 + j]
    for (int it = tid; it < 64 * 64; it += 256) {
        int c = it >> 6, l = it & 63;
        size_t src = (size_t)(n0 + (l & 15)) * RDIM + c * 32 + ((l >> 4) << 3);
        *(bf16x8*)(ldsBhi + (size_t)it * 8) = *(const bf16x8*)(Whi + src);
        *(bf16x8*)(ldsBlo + (size_t)it * 8) = *(const bf16x8*)(Wlo + src);
    }
    __syncthreads();

    // h fragment (B-operand): rows = batch m0+mt*16+l15, K-half kh
    const int hrow = m0 + mt * 16 + l15;
    const size_t hbase = (size_t)hrow * RDIM + kh * 1024 + q * 8;
    const unsigned short* wh_base = ldsBhi + (size_t)(kh * 32) * 64 * 8;
    const unsigned short* wl_base = ldsBlo + (size_t)(kh * 32) * 64 * 8;

    // epilogue (kh==0 waves): batch row b = m0+mt*16+l15, cols n0+q*4..+3 (contig)
    const int eb = m0 + mt * 16 + l15;
    const size_t obase = (size_t)eb * RDIM + n0 + q * 4;

    float hreg[4] = {0.f, 0.f, 0.f, 0.f};
    unsigned* gslot = &bar[(nb & 7) * 32];
    unsigned* gcnt  = &bar[256];

    for (int t = 1; t < TLEN; ++t) {
        const unsigned short* hphi = hb + (size_t)(((t - 1) & (HPAR - 1)) * 2) * HELEMS;
        const unsigned short* hplo = hphi + HELEMS;
        unsigned short* hchi = hb + (size_t)((t & (HPAR - 1)) * 2) * HELEMS;
        unsigned short* hclo = hchi + HELEMS;
        float* outt = hseq + (size_t)t * HELEMS;

        // prefetch U_t (hidden under the MFMA loop)
        f32x4 u4;
        if (kh == 0) u4 = *(const f32x4*)(outt + obase);

        const unsigned short* ah = hphi + hbase;
        const unsigned short* al = hplo + hbase;

        f32x4 acc0 = {0.f, 0.f, 0.f, 0.f};
        f32x4 acc1 = {0.f, 0.f, 0.f, 0.f};
        f32x4 acc2 = {0.f, 0.f, 0.f, 0.f};
        f32x4 acc3 = {0.f, 0.f, 0.f, 0.f};
#pragma unroll
        for (int c = 0; c < 32; ++c) {
            bf16x8 hhi = *(const bf16x8*)(ah + c * 32);
            bf16x8 hlo = *(const bf16x8*)(al + c * 32);
            bf16x8 whi = *(const bf16x8*)(wh_base + (size_t)(c * 64 + lane) * 8);
            bf16x8 wlo = *(const bf16x8*)(wl_base + (size_t)(c * 64 + lane) * 8);
            f32x4* a = (c & 2) ? ((c & 1) ? &acc3 : &acc2) : ((c & 1) ? &acc1 : &acc0);
            *a = __builtin_amdgcn_mfma_f32_16x16x32_bf16(whi, hhi, *a, 0, 0, 0);
            *a = __builtin_amdgcn_mfma_f32_16x16x32_bf16(whi, hlo, *a, 0, 0, 0);
            *a = __builtin_amdgcn_mfma_f32_16x16x32_bf16(wlo, hhi, *a, 0, 0, 0);
        }
        f32x4 acc;
#pragma unroll
        for (int v = 0; v < 4; ++v) acc[v] = (acc0[v] + acc1[v]) + (acc2[v] + acc3[v]);

        if (kh == 1) {
#pragma unroll
            for (int v = 0; v < 4; ++v) red[mt][q * 4 + v][l15] = acc[v];
        }
        __syncthreads();

        if (kh == 0) {
            unsigned long long phi = 0ull, plo = 0ull;
            f32x4 hout;
#pragma unroll
            for (int v = 0; v < 4; ++v) {
                float tot = acc[v] + red[mt][q * 4 + v][l15];
                float raw = tanhf(tot + u4[v]);
                float h = (t >= 2) ? 0.5f * raw + 0.5f * hreg[v] : raw;
                hreg[v] = h;
                hout[v] = h;
                unsigned short hi = f32_bf16_rne(h);
                phi |= (unsigned long long)hi << (16 * v);
                plo |= (unsigned long long)f32_bf16_rne(h - bf16_f32(hi)) << (16 * v);
            }
            *(f32x4*)(outt + obase) = hout;  // block-private, plain store
            // cross-block: write-through to coherence point (bypass L2)
            __hip_atomic_store((unsigned long long*)(hchi + obase), phi,
                               __ATOMIC_RELAXED, __HIP_MEMORY_SCOPE_AGENT);
            __hip_atomic_store((unsigned long long*)(hclo + obase), plo,
                               __ATOMIC_RELAXED, __HIP_MEMORY_SCOPE_AGENT);
        }

        if (t + 1 < TLEN) {
            // drain this wave's stores, then block-level join
            asm volatile("s_waitcnt vmcnt(0)" ::: "memory");
            __syncthreads();
            if (tid == 0) {
                unsigned old = __hip_atomic_fetch_add(gslot, 1u, __ATOMIC_RELAXED,
                                                      __HIP_MEMORY_SCOPE_AGENT);
                if (old == (unsigned)t * 32u - 1u) {
                    __hip_atomic_fetch_add(gcnt, 1u, __ATOMIC_RELAXED,
                                           __HIP_MEMORY_SCOPE_AGENT);
                }
                while (__hip_atomic_load(gcnt, __ATOMIC_RELAXED,
                                         __HIP_MEMORY_SCOPE_AGENT) < (unsigned)t * 8u) {
                    __builtin_amdgcn_s_sleep(1);
                }
            }
            __syncthreads();
            asm volatile("" ::: "memory");
            // stale-line invalidate only once per HPAR steps (rotation guarantees
            // freshness otherwise; keeps L2 warm for intra-XCD h sharing)
            if (((t + 1) & (HPAR - 1)) == 0)
                __builtin_amdgcn_fence(__ATOMIC_ACQUIRE, "agent");
        }
    }
}

// ---------------- Fallback step kernel (no workspace) ----------------
__global__ __launch_bounds__(256) void k_step_f32(float* hseq,
                                                  const float* __restrict__ Wf,
                                                  int t) {
    const int lane = threadIdx.x & 63;
    const int wave = threadIdx.x >> 6;
    const int l15 = lane & 15;
    const int q = lane >> 4;
    const int n0 = blockIdx.x * 16;
    const int m0 = wave * 16;

    const int arow = m0 + l15;
    const int brow = n0 + l15;
    const int kbase = q * 8;

    f32x4 acc = {0.f, 0.f, 0.f, 0.f};
    const float* hprev_f = hseq + (size_t)(t - 1) * BATCH * RDIM;
    const float* af = hprev_f + arow * RDIM + kbase;
    const float* bfp = Wf + brow * RDIM + kbase;
#pragma unroll 2
    for (int k = 0; k < RDIM; k += 32) {
        f32x4 a0 = *(const f32x4*)(af + k);
        f32x4 a1 = *(const f32x4*)(af + k + 4);
        f32x4 b0 = *(const f32x4*)(bfp + k);
        f32x4 b1 = *(const f32x4*)(bfp + k + 4);
        bf16x8 ahi, alo, bhi, blo;
#pragma unroll
        for (int j = 0; j < 4; ++j) {
            unsigned short h;
            h = f32_bf16_rne(a0[j]); ahi[j] = (short)h; alo[j] = (short)f32_bf16_rne(a0[j] - bf16_f32(h));
            h = f32_bf16_rne(a1[j]); ahi[4 + j] = (short)h; alo[4 + j] = (short)f32_bf16_rne(a1[j] - bf16_f32(h));
            h = f32_bf16_rne(b0[j]); bhi[j] = (short)h; blo[j] = (short)f32_bf16_rne(b0[j] - bf16_f32(h));
            h = f32_bf16_rne(b1[j]); bhi[4 + j] = (short)h; blo[4 + j] = (short)f32_bf16_rne(b1[j] - bf16_f32(h));
        }
        acc = __builtin_amdgcn_mfma_f32_16x16x32_bf16(ahi, bhi, acc, 0, 0, 0);
        acc = __builtin_amdgcn_mfma_f32_16x16x32_bf16(alo, bhi, acc, 0, 0, 0);
        acc = __builtin_amdgcn_mfma_f32_16x16x32_bf16(ahi, blo, acc, 0, 0, 0);
    }

    float* outt = hseq + (size_t)t * BATCH * RDIM;
#pragma unroll
    for (int v = 0; v < 4; ++v) {
        int b = m0 + q * 4 + v;
        size_t o = (size_t)b * RDIM + brow;
        float raw = tanhf(acc[v] + outt[o]);
        float hp = hprev_f[o];
        float h = (t >= 2) ? 0.5f * raw + 0.5f * hp : raw;
        outt[o] = h;
    }
}

extern "C" void kernel_launch(void* const* d_in, const int* in_sizes, int n_in,
                              void* d_out, int out_size, void* d_ws, size_t ws_size,
                              hipStream_t stream) {
    const float* x   = (const float*)d_in[0];
    const float* Win = (const float*)d_in[1];
    const float* W   = (const float*)d_in[2];
    float* out = (float*)d_out;

    const size_t wElems = (size_t)RDIM * RDIM;
    const size_t hElems = (size_t)BATCH * RDIM;
    const size_t need = wElems * 2 * sizeof(unsigned short) +
                        (size_t)HPAR * 2 * hElems * sizeof(unsigned short) + 4096;
    const bool split = ws_size >= need;

    unsigned short* Whi = (unsigned short*)d_ws;
    unsigned short* Wlo = Whi + wElems;
    unsigned short* hb  = Wlo + wElems;
    unsigned* bar = (unsigned*)(hb + (size_t)HPAR * 2 * hElems);
    unsigned short* h0hi = hb;            // hi buffer for t=0 (parity 0)
    unsigned short* h0lo = hb + hElems;   // lo buffer for t=0

    if (split) {
        k_wsplit<<<(int)(wElems / 1024), 256, 0, stream>>>(W, Whi, Wlo, bar);
    }

    dim3 gA(RDIM / A_BN, (BATCH * TLEN) / A_BM);
    k_proj<<<gA, 256, 0, stream>>>(x, Win, out, split ? h0hi : nullptr,
                                   split ? h0lo : nullptr, split ? 1 : 0);

    if (split) {
        float* outp = out;
        unsigned short* Whip = Whi;
        unsigned short* Wlop = Wlo;
        unsigned short* hbp = hb;
        unsigned* barp = bar;
        void* args[5] = { &outp, &Whip, &Wlop, &hbp, &barp };
        hipLaunchCooperativeKernel((const void*)k_steps, dim3(256), dim3(256),
                                   args, 0, stream);
    } else {
        for (int t = 1; t < TLEN; ++t) {
            k_step_f32<<<RDIM / 16, 256, 0, stream>>>(out, W, t);
        }
    }
}